// Round 3
// baseline (430.766 us; speedup 1.0000x reference)
//
#include <hip/hip_runtime.h>

#define D     384
#define E     769      // 1 + 2*D
#define NTOK  4096
#define BPN   32       // B*P
#define NROWS (BPN*NTOK)

typedef short s16x8 __attribute__((ext_vector_type(8)));
typedef float f32x4 __attribute__((ext_vector_type(4)));

__device__ __forceinline__ unsigned short f2bf(float f){
  unsigned int u = __builtin_bit_cast(unsigned int, f);
  u += 0x7FFFu + ((u >> 16) & 1u);          // round-to-nearest-even
  return (unsigned short)(u >> 16);
}

// ---------------- K0: pack wq; build FRAGMENT-ORDERED bf16 weights ----------------
// frag idx f = ((ntile*12 + kt)*64 + lane)*8 + pos ; lane = l4*16+l15
// element   = W[k = kt*32 + l4*8 + pos][col = ntile*16 + l15]
__global__ void k0_prep(const float* __restrict__ wqkv, const float* __restrict__ wout,
                        float* __restrict__ wq, unsigned short* __restrict__ wvF,
                        unsigned short* __restrict__ woF){
  int tid = blockIdx.x*256 + threadIdx.x;     // 0 .. 147455
  if (tid < D) wq[tid] = wqkv[(size_t)tid*E];              // w_qkv[:,0]
  if (tid < 24*12*64*8){
    int pos = tid & 7;
    int lane = (tid >> 3) & 63;
    int kt  = (tid >> 9) % 12;
    int nt  = tid / 6144;
    int l15 = lane & 15, l4 = lane >> 4;
    int col = nt*16 + l15;
    int k   = kt*32 + l4*8 + pos;
    wvF[tid] = f2bf(wqkv[(size_t)k*E + 385 + col]);        // wv[k][col]
    woF[tid] = f2bf(wout[(size_t)k*D + col]);              // wout[k][col]
  }
}

// ---------------- kA: fused q + chunk-softmax + weighted row-sum ----------------
// per (bp, chunk of 128 rows): m_c, l_c, partial_c[384] = sum_n exp(q_n - m_c) H_n
__global__ void kA_fused(const float* __restrict__ H, const float* __restrict__ wq,
                         float* __restrict__ partial, float* __restrict__ mArr,
                         float* __restrict__ lArr){
  __shared__ float qs[128];
  __shared__ float ws[128];
  const int ch = blockIdx.x, bp = blockIdx.y;
  const size_t base = (size_t)bp*NTOK + (size_t)ch*128;
  const int t = threadIdx.x;                 // 384 threads, 6 waves
  const int wave = t >> 6, lane = t & 63;

  // phase A: q_r = H[r,:].wq  (softmax is shift-invariant -> bias drops)
  for (int r = wave; r < 128; r += 6){
    const float* hr = H + (base + r)*D;
    float a = 0.f;
    #pragma unroll
    for (int seg = 0; seg < 3; ++seg){
      int k = lane*2 + seg*128;
      float2 h = *reinterpret_cast<const float2*>(hr + k);
      float2 w = *reinterpret_cast<const float2*>(wq + k);
      a += h.x*w.x + h.y*w.y;
    }
    #pragma unroll
    for (int off=32; off; off>>=1) a += __shfl_xor(a, off, 64);
    if (lane == 0) qs[r] = a;
  }
  __syncthreads();

  // chunk softmax weights (wave 0 handles all 128)
  if (wave == 0){
    float a0 = qs[lane], a1 = qs[lane+64];
    float mm = fmaxf(a0, a1);
    #pragma unroll
    for (int off=32; off; off>>=1) mm = fmaxf(mm, __shfl_xor(mm, off, 64));
    float e0 = __expf(a0 - mm), e1 = __expf(a1 - mm);
    ws[lane] = e0; ws[lane+64] = e1;
    float sum = e0 + e1;
    #pragma unroll
    for (int off=32; off; off>>=1) sum += __shfl_xor(sum, off, 64);
    if (lane == 0){ mArr[bp*32 + ch] = mm; lArr[bp*32 + ch] = sum; }
  }
  __syncthreads();

  // phase B: partial[col] = sum_n ws[n] * H[n][col]  (re-read, L2-hot)
  float acc = 0.f;
  #pragma unroll 4
  for (int n = 0; n < 128; ++n)
    acc += ws[n] * H[(base + n)*D + t];
  partial[((size_t)bp*32 + ch)*D + t] = acc;
}

// ---------------- kB: combine chunks -> cv[bp][j] ----------------
__global__ void kB_cv(const float* __restrict__ partial, const float* __restrict__ mArr,
                      const float* __restrict__ lArr, const float* __restrict__ wqkv,
                      const float* __restrict__ bqkv, float* __restrict__ cv){
  __shared__ float S[D];
  const int bp = blockIdx.x, t = threadIdx.x;   // 384 threads
  float M = -3.4e38f;
  #pragma unroll 4
  for (int c = 0; c < 32; ++c) M = fmaxf(M, mArr[bp*32 + c]);
  float num = 0.f, den = 0.f;
  #pragma unroll 2
  for (int c = 0; c < 32; ++c){
    float f = __expf(mArr[bp*32 + c] - M);
    num += f * partial[((size_t)bp*32 + c)*D + t];
    den += f * lArr[bp*32 + c];
  }
  S[t] = num / den;
  __syncthreads();
  float acc = bqkv[1 + t];
  #pragma unroll 4
  for (int k = 0; k < D; ++k)
    acc += S[k] * wqkv[(size_t)k*E + 1 + t];
  cv[(size_t)bp*D + t] = acc;
}

// ---------------- K5: per 32-row block: out = relu(A@wv + bv)*cv @ Wout + bout ----------------
#define BM 32

__global__ __launch_bounds__(256, 4)
void k5_main(const float* __restrict__ H, const unsigned short* __restrict__ wvF,
             const unsigned short* __restrict__ woF, const float* __restrict__ cv,
             const float* __restrict__ bqkv, const float* __restrict__ bout,
             float* __restrict__ out){
  // union: bf16 frag-ordered A/R tile (24576 B)  |  fp32 store slab [16][388] (24832 B)
  __shared__ char smem[16*388*4];
  unsigned short* As = (unsigned short*)smem;
  float*          Fs = (float*)smem;

  const int bp = blockIdx.y;
  const int m0 = blockIdx.x*BM;
  const size_t rowbase = (size_t)bp*NTOK + m0;
  const float* A = H + rowbase*D;
  const int t = threadIdx.x;

  // stage H (fp32, coalesced) -> bf16 LDS in FRAGMENT order
  #pragma unroll
  for (int i=0;i<12;++i){
    int c = t + i*256;                   // 0..3071 (float4 chunks)
    int idx8 = c >> 1;
    int l15v = idx8 & 15;
    int l4v  = (idx8 >> 4) & 3;
    int ktv  = (idx8 >> 6) % 12;
    int mv   = idx8 / 768;
    float4 v = *reinterpret_cast<const float4*>(
        A + (size_t)(mv*16 + l15v)*D + ktv*32 + l4v*8 + (c&1)*4);
    ushort4 b;
    b.x=f2bf(v.x); b.y=f2bf(v.y); b.z=f2bf(v.z); b.w=f2bf(v.w);
    *reinterpret_cast<ushort4*>(&As[c*4]) = b;
  }
  __syncthreads();

  const int wave = t>>6, lane = t&63;
  const int l15 = lane&15, l4 = lane>>4;
  const int n0 = wave*96;                      // each of 4 waves owns 96 output cols
  const unsigned short* wvW = wvF + (size_t)wave*6*12*512;
  const unsigned short* woW = woF + (size_t)wave*6*12*512;

  f32x4 acc[2][6] = {};
  // GEMM1: v = A @ wv
  #pragma unroll
  for (int kt=0; kt<12; ++kt){
    s16x8 a[2], b[6];
    #pragma unroll
    for (int m=0;m<2;++m)
      a[m] = *reinterpret_cast<const s16x8*>(&As[((m*12+kt)*64 + lane)*8]);
    #pragma unroll
    for (int n=0;n<6;++n)
      b[n] = *reinterpret_cast<const s16x8*>(&wvW[((size_t)(n*12+kt)*64 + lane)*8]);
    #pragma unroll
    for (int m=0;m<2;++m)
      #pragma unroll
      for (int n=0;n<6;++n)
        acc[m][n] = __builtin_amdgcn_mfma_f32_16x16x32_bf16(a[m], b[n], acc[m][n], 0,0,0);
  }
  __syncthreads();   // everyone done reading As before overwrite

  // epilogue1: r = relu(v + bv) * cv  -> bf16 back into As in FRAGMENT order
  #pragma unroll
  for (int n=0;n<6;++n){
    int col = n0 + n*16 + l15;
    float bv  = bqkv[385+col];
    float cvv = cv[(size_t)bp*D + col];
    int kt2 = col >> 5;
    int l42 = (col >> 3) & 3;
    int pos2 = col & 7;
    #pragma unroll
    for (int m=0;m<2;++m){
      #pragma unroll
      for (int r=0;r<4;++r){
        int row = l4*4 + r;
        float v = acc[m][n][r] + bv;
        v = v > 0.f ? v*cvv : 0.f;
        As[((m*12+kt2)*64 + l42*16 + row)*8 + pos2] = f2bf(v);
      }
    }
  }
  #pragma unroll
  for (int m=0;m<2;++m)
    #pragma unroll
    for (int n=0;n<6;++n)
      acc[m][n] = (f32x4){0.f,0.f,0.f,0.f};
  __syncthreads();

  // GEMM2: out = R @ Wout
  #pragma unroll
  for (int kt=0; kt<12; ++kt){
    s16x8 a[2], b[6];
    #pragma unroll
    for (int m=0;m<2;++m)
      a[m] = *reinterpret_cast<const s16x8*>(&As[((m*12+kt)*64 + lane)*8]);
    #pragma unroll
    for (int n=0;n<6;++n)
      b[n] = *reinterpret_cast<const s16x8*>(&woW[((size_t)(n*12+kt)*64 + lane)*8]);
    #pragma unroll
    for (int m=0;m<2;++m)
      #pragma unroll
      for (int n=0;n<6;++n)
        acc[m][n] = __builtin_amdgcn_mfma_f32_16x16x32_bf16(a[m], b[n], acc[m][n], 0,0,0);
  }
  __syncthreads();   // done reading As; Fs reuse below

  // epilogue2: round-trip through fp32 LDS, stream out as contiguous 24KB slabs
  #pragma unroll
  for (int p=0; p<2; ++p){            // pass p stores m-tile p (16 rows)
    #pragma unroll
    for (int n=0;n<6;++n){
      int col = n0 + n*16 + l15;
      float bo = bout[col];
      #pragma unroll
      for (int r=0;r<4;++r)
        Fs[(l4*4 + r)*388 + col] = acc[p][n][r] + bo;
    }
    __syncthreads();
    #pragma unroll
    for (int i=0;i<6;++i){
      int idx = t + i*256;            // 0..1535 float4
      int row = idx/96, c4 = idx%96;
      float4 v = *reinterpret_cast<const float4*>(&Fs[row*388 + c4*4]);
      *reinterpret_cast<float4*>(&out[(rowbase + p*16 + row)*D + c4*4]) = v;
    }
    __syncthreads();
  }
}

extern "C" void kernel_launch(void* const* d_in, const int* in_sizes, int n_in,
                              void* d_out, int out_size, void* d_ws, size_t ws_size,
                              hipStream_t stream){
  const float* H    = (const float*)d_in[0];
  const float* wqkv = (const float*)d_in[1];
  const float* bqkv = (const float*)d_in[2];
  const float* wout = (const float*)d_in[3];
  const float* bout = (const float*)d_in[4];
  float* out = (float*)d_out;

  char* ws = (char*)d_ws;
  float*          partial = (float*)(ws + 0x000000);   // 32*32*384*4 = 1.5 MB
  float*          mArr    = (float*)(ws + 0x180000);   // 4 KB
  float*          lArr    = (float*)(ws + 0x181000);   // 4 KB
  float*          cv      = (float*)(ws + 0x182000);   // 48 KB slot
  float*          wq      = (float*)(ws + 0x190000);   // 4 KB slot
  unsigned short* wvF     = (unsigned short*)(ws + 0x191000);  // 288 KB
  unsigned short* woF     = (unsigned short*)(ws + 0x1D9000);  // 288 KB (end 0x221000)

  hipLaunchKernelGGL(k0_prep,  dim3(576),          dim3(256), 0, stream, wqkv, wout, wq, wvF, woF);
  hipLaunchKernelGGL(kA_fused, dim3(32, BPN),      dim3(384), 0, stream, H, wq, partial, mArr, lArr);
  hipLaunchKernelGGL(kB_cv,    dim3(BPN),          dim3(384), 0, stream, partial, mArr, lArr, wqkv, bqkv, cv);
  hipLaunchKernelGGL(k5_main,  dim3(NTOK/BM, BPN), dim3(256), 0, stream, H, wvF, woF, cv, bqkv, bout, out);
}

// Round 5
// 334.182 us; speedup vs baseline: 1.2890x; 1.2890x over previous
//
#include <hip/hip_runtime.h>

#define D     384
#define E     769      // 1 + 2*D
#define NTOK  4096
#define BPN   32       // B*P
#define NROWS (BPN*NTOK)
#define NCH   32       // chunks of 128 rows per (b,p)

typedef short s16x8 __attribute__((ext_vector_type(8)));
typedef float f32x4 __attribute__((ext_vector_type(4)));
typedef float f32x2 __attribute__((ext_vector_type(2)));

__device__ __forceinline__ unsigned short f2bf(float f){
  unsigned int u = __builtin_bit_cast(unsigned int, f);
  u += 0x7FFFu + ((u >> 16) & 1u);          // round-to-nearest-even
  return (unsigned short)(u >> 16);
}

// ---------------- K0: pack wq; build FRAGMENT-ORDERED bf16 weights ----------------
// frag idx f = ((ntile*12 + kt)*64 + lane)*8 + pos ; lane = l4*16+l15
// element   = W[k = kt*32 + l4*8 + pos][col = ntile*16 + l15]
__global__ void k0_prep(const float* __restrict__ wqkv, const float* __restrict__ wout,
                        float* __restrict__ wq, unsigned short* __restrict__ wvF,
                        unsigned short* __restrict__ woF){
  int tid = blockIdx.x*256 + threadIdx.x;     // 0 .. 147455
  if (tid < D) wq[tid] = wqkv[(size_t)tid*E];              // w_qkv[:,0]
  if (tid < 24*12*64*8){
    int pos = tid & 7;
    int lane = (tid >> 3) & 63;
    int kt  = (tid >> 9) % 12;
    int nt  = tid / 6144;
    int l15 = lane & 15, l4 = lane >> 4;
    int col = nt*16 + l15;
    int k   = kt*32 + l4*8 + pos;
    wvF[tid] = f2bf(wqkv[(size_t)k*E + 385 + col]);        // wv[k][col]
    woF[tid] = f2bf(wout[(size_t)k*D + col]);              // wout[k][col]
  }
}

// ---------------- kA: fused q + ONLINE chunk-softmax + weighted row-sum ----------------
// per (bp, chunk of 128 rows): 4 sub-tiles of 32 rows staged in LDS fp32;
// online (m,l,acc) update; single global H pass.
__global__ __launch_bounds__(384)
void kA_fused(const float* __restrict__ H, const float* __restrict__ wq,
              float* __restrict__ partial, float* __restrict__ mArr,
              float* __restrict__ lArr){
  __shared__ float Hs[32][D];   // 48 KB
  __shared__ float qs[32];
  const int ch = blockIdx.x, bp = blockIdx.y;
  const int t = threadIdx.x;                 // 384 threads, 6 waves
  const int wave = t >> 6, lane = t & 63;

  float acc = 0.f, mRun = -3.4e38f, lRun = 0.f;

  for (int s = 0; s < 4; ++s){
    if (s) __syncthreads();                  // prev phase-B readers done
    const size_t base = (size_t)bp*NTOK + (size_t)ch*128 + s*32;

    // stage 32 rows (nt, single touch) + per-row dot with wq
    for (int r = wave; r < 32; r += 6){
      const float* hr = H + (base + r)*D;
      float a = 0.f;
      #pragma unroll
      for (int seg = 0; seg < 3; ++seg){
        int k = lane*2 + seg*128;
        f32x2 h = __builtin_nontemporal_load(reinterpret_cast<const f32x2*>(hr + k));
        f32x2 w = *reinterpret_cast<const f32x2*>(wq + k);
        a += h.x*w.x + h.y*w.y;
        *reinterpret_cast<f32x2*>(&Hs[r][k]) = h;
      }
      #pragma unroll
      for (int off=32; off; off>>=1) a += __shfl_xor(a, off, 64);
      if (lane == 0) qs[r] = a;
    }
    __syncthreads();

    // online update (all threads compute identical m/l; acc is per-column t)
    float msub = qs[0];
    #pragma unroll 8
    for (int n=1;n<32;++n) msub = fmaxf(msub, qs[n]);
    float mNew  = fmaxf(mRun, msub);
    float scale = __expf(mRun - mNew);       // first iter: exp(-3.4e38) = 0
    acc  *= scale;
    lRun *= scale;
    float lsub = 0.f;
    #pragma unroll 4
    for (int n=0;n<32;++n){
      float w = __expf(qs[n] - mNew);
      lsub += w;
      acc  += w * Hs[n][t];
    }
    lRun += lsub;
    mRun  = mNew;
  }

  partial[((size_t)bp*NCH + ch)*D + t] = acc;
  if (t == 0){ mArr[bp*NCH + ch] = mRun; lArr[bp*NCH + ch] = lRun; }
}

// ---------------- kB: combine chunks -> cv[bp][j] ----------------
__global__ void kB_cv(const float* __restrict__ partial, const float* __restrict__ mArr,
                      const float* __restrict__ lArr, const float* __restrict__ wqkv,
                      const float* __restrict__ bqkv, float* __restrict__ cv){
  __shared__ float S[D];
  const int bp = blockIdx.x, t = threadIdx.x;   // 384 threads
  float M = -3.4e38f;
  #pragma unroll 4
  for (int c = 0; c < NCH; ++c) M = fmaxf(M, mArr[bp*NCH + c]);
  float num = 0.f, den = 0.f;
  #pragma unroll 2
  for (int c = 0; c < NCH; ++c){
    float f = __expf(mArr[bp*NCH + c] - M);
    num += f * partial[((size_t)bp*NCH + c)*D + t];
    den += f * lArr[bp*NCH + c];
  }
  S[t] = num / den;
  __syncthreads();
  float acc = bqkv[1 + t];
  #pragma unroll 4
  for (int k = 0; k < D; ++k)
    acc += S[k] * wqkv[(size_t)k*E + 1 + t];
  cv[(size_t)bp*D + t] = acc;
}

// ---------------- K5: per 64-row block: out = relu(A@wv + bv)*cv @ Wout + bout ----------------
#define BM 64

__global__ __launch_bounds__(256, 3)
void k5_main(const float* __restrict__ H, const unsigned short* __restrict__ wvF,
             const unsigned short* __restrict__ woF, const float* __restrict__ cv,
             const float* __restrict__ bqkv, const float* __restrict__ bout,
             float* __restrict__ out){
  // union: bf16 frag-ordered A/R tile (49152 B) | fp32 store slab [16][388] (24832 B)
  __shared__ char smem[BM*D*2];
  unsigned short* As = (unsigned short*)smem;
  float*          Fs = (float*)smem;

  const int bp = blockIdx.y;
  const int m0 = blockIdx.x*BM;
  const size_t rowbase = (size_t)bp*NTOK + m0;
  const float* A = H + rowbase*D;
  const int t = threadIdx.x;

  // stage H (fp32, nt, coalesced) -> bf16 LDS in FRAGMENT order
  #pragma unroll
  for (int i=0;i<24;++i){
    int c = t + i*256;                   // 0..6143 (float4 chunks)
    int idx8 = c >> 1;
    int l15v = idx8 & 15;
    int l4v  = (idx8 >> 4) & 3;
    int ktv  = (idx8 >> 6) % 12;
    int mv   = idx8 / 768;
    f32x4 v = __builtin_nontemporal_load(reinterpret_cast<const f32x4*>(
        A + (size_t)(mv*16 + l15v)*D + ktv*32 + l4v*8 + (c&1)*4));
    ushort4 b;
    b.x=f2bf(v.x); b.y=f2bf(v.y); b.z=f2bf(v.z); b.w=f2bf(v.w);
    *reinterpret_cast<ushort4*>(&As[c*4]) = b;
  }
  __syncthreads();

  const int wave = t>>6, lane = t&63;
  const int l15 = lane&15, l4 = lane>>4;
  const int n0 = wave*96;                      // each of 4 waves owns 96 output cols
  const unsigned short* wvW = wvF + (size_t)wave*6*12*512;
  const unsigned short* woW = woF + (size_t)wave*6*12*512;

  f32x4 acc[4][6] = {};
  // GEMM1: v = A @ wv  (b-frags contiguous 1KB/wave, L2-resident)
  #pragma unroll
  for (int kt=0; kt<12; ++kt){
    s16x8 a[4], b[6];
    #pragma unroll
    for (int m=0;m<4;++m)
      a[m] = *reinterpret_cast<const s16x8*>(&As[((m*12+kt)*64 + lane)*8]);
    #pragma unroll
    for (int n=0;n<6;++n)
      b[n] = *reinterpret_cast<const s16x8*>(&wvW[((size_t)(n*12+kt)*64 + lane)*8]);
    #pragma unroll
    for (int m=0;m<4;++m)
      #pragma unroll
      for (int n=0;n<6;++n)
        acc[m][n] = __builtin_amdgcn_mfma_f32_16x16x32_bf16(a[m], b[n], acc[m][n], 0,0,0);
  }
  __syncthreads();   // everyone done reading As before overwrite

  // epilogue1: r = relu(v + bv) * cv  -> bf16 back into As in FRAGMENT order
  #pragma unroll
  for (int n=0;n<6;++n){
    int col = n0 + n*16 + l15;
    float bv  = bqkv[385+col];
    float cvv = cv[(size_t)bp*D + col];
    int kt2 = col >> 5;
    int l42 = (col >> 3) & 3;
    int pos2 = col & 7;
    #pragma unroll
    for (int m=0;m<4;++m){
      #pragma unroll
      for (int r=0;r<4;++r){
        int row = l4*4 + r;
        float v = acc[m][n][r] + bv;
        v = v > 0.f ? v*cvv : 0.f;
        As[((m*12+kt2)*64 + l42*16 + row)*8 + pos2] = f2bf(v);
      }
    }
  }
  #pragma unroll
  for (int m=0;m<4;++m)
    #pragma unroll
    for (int n=0;n<6;++n)
      acc[m][n] = (f32x4){0.f,0.f,0.f,0.f};
  __syncthreads();

  // GEMM2: out = R @ Wout
  #pragma unroll
  for (int kt=0; kt<12; ++kt){
    s16x8 a[4], b[6];
    #pragma unroll
    for (int m=0;m<4;++m)
      a[m] = *reinterpret_cast<const s16x8*>(&As[((m*12+kt)*64 + lane)*8]);
    #pragma unroll
    for (int n=0;n<6;++n)
      b[n] = *reinterpret_cast<const s16x8*>(&woW[((size_t)(n*12+kt)*64 + lane)*8]);
    #pragma unroll
    for (int m=0;m<4;++m)
      #pragma unroll
      for (int n=0;n<6;++n)
        acc[m][n] = __builtin_amdgcn_mfma_f32_16x16x32_bf16(a[m], b[n], acc[m][n], 0,0,0);
  }
  __syncthreads();   // done reading As; Fs reuse below

  // epilogue2: per 16-row m-tile, round-trip through fp32 LDS, stream out
  // as fully-contiguous 24 KB slabs with non-temporal full-line stores.
  #pragma unroll
  for (int p=0; p<4; ++p){
    #pragma unroll
    for (int n=0;n<6;++n){
      int col = n0 + n*16 + l15;
      float bo = bout[col];
      #pragma unroll
      for (int r=0;r<4;++r)
        Fs[(l4*4 + r)*388 + col] = acc[p][n][r] + bo;
    }
    __syncthreads();
    #pragma unroll
    for (int i=0;i<6;++i){
      int idx = t + i*256;            // 0..1535 float4
      int row = idx/96, c4 = idx%96;
      f32x4 v = *reinterpret_cast<const f32x4*>(&Fs[row*388 + c4*4]);
      __builtin_nontemporal_store(v, reinterpret_cast<f32x4*>(
          &out[(rowbase + p*16 + row)*D + c4*4]));
    }
    __syncthreads();
  }
}

extern "C" void kernel_launch(void* const* d_in, const int* in_sizes, int n_in,
                              void* d_out, int out_size, void* d_ws, size_t ws_size,
                              hipStream_t stream){
  const float* H    = (const float*)d_in[0];
  const float* wqkv = (const float*)d_in[1];
  const float* bqkv = (const float*)d_in[2];
  const float* wout = (const float*)d_in[3];
  const float* bout = (const float*)d_in[4];
  float* out = (float*)d_out;

  char* ws = (char*)d_ws;                              // total usage: 2.13 MB
  float*          partial = (float*)(ws + 0x000000);   // 32*32*384*4 = 1.5 MB
  float*          mArr    = (float*)(ws + 0x180000);   // 4 KB
  float*          lArr    = (float*)(ws + 0x181000);   // 4 KB
  float*          cv      = (float*)(ws + 0x182000);   // 48 KB
  float*          wq      = (float*)(ws + 0x18E000);   // 1.5 KB
  unsigned short* wvF     = (unsigned short*)(ws + 0x190000);  // 288 KB
  unsigned short* woF     = (unsigned short*)(ws + 0x1D8000);  // 288 KB (end 0x220000)

  hipLaunchKernelGGL(k0_prep,  dim3(576),          dim3(256), 0, stream, wqkv, wout, wq, wvF, woF);
  hipLaunchKernelGGL(kA_fused, dim3(NCH, BPN),     dim3(384), 0, stream, H, wq, partial, mArr, lArr);
  hipLaunchKernelGGL(kB_cv,    dim3(BPN),          dim3(384), 0, stream, partial, mArr, lArr, wqkv, bqkv, cv);
  hipLaunchKernelGGL(k5_main,  dim3(NTOK/BM, BPN), dim3(256), 0, stream, H, wvF, woF, cv, bqkv, bout, out);
}